// Round 6
// baseline (776.756 us; speedup 1.0000x reference)
//
#include <hip/hip_runtime.h>

// Problem constants: B=1048576, T=11, F=3, H=11, C=7
#define TT 11
#define FF 3
#define HH 11
#define CC 7
#define TF 33      // T*F
#define BLOCK 256
#define L2E 1.44269504088896340736f

typedef _Float16 h4 __attribute__((ext_vector_type(4)));   // one MFMA A/B fragment (2 VGPRs)
typedef float f4 __attribute__((ext_vector_type(4)));      // one MFMA C/D fragment
typedef unsigned int u2 __attribute__((ext_vector_type(2)));

// ws layout (dwords):
//  [0..511]    gate A-fragments  [4 gates][64 lanes][2 dwords]  (PRE-SCALED by -log2e / -2log2e)
//  [512..1919] dense A-fragments [11 t   ][64 lanes][2 dwords]
#define WS_GA 0
#define WS_DA 512
#define WS_TOT 1920

// Augmented weight matrix value, transposed form A'[row=n(gate out)][k]:
//  k=0..10 -> h_k coefficient, k=11..13 -> x_{k-11} coefficient, k=14 -> bias (B row 14 = 1.0), k=15 -> 0
__device__ __forceinline__ float gate_val(int g, int k, int n,
        const float* rk, const float* kk, const float* bias) {
    if (n >= HH) return 0.0f;
    if (g == 0 || g == 1) {            // z, r: full augmented row
        const int col = (g == 0 ? 0 : HH) + n;
        if (k < HH) return rk[k * TF + col];
        if (k < 14) return kk[(k - 11) * TF + col];
        if (k == 14) return bias[col] + bias[TF + col];
        return 0.0f;
    }
    const int col = 2 * HH + n;
    if (g == 2) {                      // rh: recurrent candidate part (+ recurrent bias)
        if (k < HH) return rk[k * TF + col];
        if (k == 14) return bias[TF + col];
        return 0.0f;
    }
    // g == 3, xh: input candidate part (+ input bias)
    if (k >= 11 && k < 14) return kk[(k - 11) * TF + col];
    if (k == 14) return bias[col];
    return 0.0f;
}

__global__ void prep_weights(const float* __restrict__ k,
                             const float* __restrict__ rk,
                             const float* __restrict__ bias,
                             const float* __restrict__ dw,
                             const float* __restrict__ db,
                             float* __restrict__ ws) {
    const int tid = threadIdx.x;
    unsigned int* wsu = (unsigned int*)ws;
    // gate A-frags: one (gate, lane) pair per thread (4*64 = 256)
    // Pre-scale: z,r rows by -log2e (so exp2(az') = e^{-az}); rh,xh rows by -2log2e.
    {
        const int g = tid >> 6, l = tid & 63;
        const int n = l & 15, kb = 4 * (l >> 4);
        const float scale = (g < 2) ? -L2E : (-2.0f * L2E);
        unsigned short h[4];
        #pragma unroll
        for (int i = 0; i < 4; ++i) {
            const float v = gate_val(g, kb + i, n, rk, k, bias) * scale;
            h[i] = __builtin_bit_cast(unsigned short, (_Float16)v);
        }
        wsu[WS_GA + (g * 64 + l) * 2]     = h[0] | ((unsigned int)h[1] << 16);
        wsu[WS_GA + (g * 64 + l) * 2 + 1] = h[2] | ((unsigned int)h[3] << 16);
    }
    // dense A-frags: A'_t[row=c][k] = dw_t[k][c] for k<11; k=14,t=0 -> db[c] (ones-row trick)
    for (int idx = tid; idx < TT * 64; idx += BLOCK) {
        const int t = idx >> 6, l = idx & 63;
        const int c = l & 15, kb = 4 * (l >> 4);
        unsigned short h[4];
        #pragma unroll
        for (int i = 0; i < 4; ++i) {
            const int kk2 = kb + i;
            float v = 0.0f;
            if (c < CC) {
                if (kk2 < HH) v = dw[(t * HH + kk2) * CC + c];
                else if (kk2 == 14 && t == 0) v = db[c];
            }
            h[i] = __builtin_bit_cast(unsigned short, (_Float16)v);
        }
        wsu[WS_DA + idx * 2]     = h[0] | ((unsigned int)h[1] << 16);
        wsu[WS_DA + idx * 2 + 1] = h[2] | ((unsigned int)h[3] << 16);
    }
}

__device__ __forceinline__ unsigned int pkf16(float a, float b) {
    return (unsigned int)__builtin_bit_cast(unsigned short, (_Float16)a) |
           ((unsigned int)__builtin_bit_cast(unsigned short, (_Float16)b) << 16);
}

__global__ __launch_bounds__(BLOCK, 7) void gru_main(
    const float* __restrict__ x,   // [B, T*F] f32
    const float* __restrict__ ws,  // fragment-ordered weights
    float* __restrict__ out,       // [B, C]
    int Bt)
{
    // compact x stage: 6 B per (b,t) -> total 16896 B; + dense frags 5632 B = 22528 B -> 7 blocks/CU
    __shared__ unsigned int   sxA[BLOCK * TT];    // (x1,x2) f16 pair       11264 B
    __shared__ unsigned short sxB[BLOCK * TT];    // x0 f16                  5632 B
    __shared__ float sda[TT * 128];               // dense A-frags           5632 B
    const int tid = threadIdx.x;
    const long long base = (long long)blockIdx.x * BLOCK;

    // dense A-frags -> LDS (coalesced, once)
    for (int i = tid; i < TT * 128; i += BLOCK) sda[i] = ws[WS_DA + i];

    const int lane = tid & 63, wave = tid >> 6;
    // gate A-frags -> registers (8 VGPRs total; all GRU weights+biases, pre-scaled)
    const h4* gfp = (const h4*)ws;
    const h4 Az  = gfp[lane];
    const h4 Ar  = gfp[64 + lane];
    const h4 Arh = gfp[128 + lane];
    const h4 Axh = gfp[192 + lane];

    // ---- coalesced x stage, f16-packed compact ----
    {
        const long long gbase = base * TF;
        const long long gmax = (long long)Bt * TF;
        unsigned short* sxA16 = (unsigned short*)sxA;
        #pragma unroll
        for (int i = 0; i < TF; ++i) {
            const int e = tid + i * BLOCK;
            const long long g = gbase + e;
            const float v = (g < gmax) ? x[g] : 0.0f;
            const int b = e / TF, r = e % TF;
            const int t = r / FF, s = r % FF;
            const unsigned short hv = __builtin_bit_cast(unsigned short, (_Float16)v);
            if (s == 0) sxB[b * TT + t] = hv;                   // x0
            else        sxA16[(b * TT + t) * 2 + (s - 1)] = hv; // (x1,x2)
        }
    }
    __syncthreads();

    const int q = lane & 15, p = lane >> 4;

    // Per-tile state: hD[k2][r] = h[j = 4p+r][b = 16*k2 + q]  (D-fragment layout)
    // Invariants (A rows >= 11 are zero + nonlinearity maps 0 -> exactly 0):
    //   p==3: hD[k2][*] == 0 ; p==2: hD[k2][3] == 0  -> B-build can use plain ORs.
    float hD[4][4];
    f4 dC[4];
    #pragma unroll
    for (int k2 = 0; k2 < 4; ++k2) {
        dC[k2] = (f4){0.f, 0.f, 0.f, 0.f};
        #pragma unroll
        for (int r = 0; r < 4; ++r) hD[k2][r] = 0.0f;
    }

    const int ibq = (wave * 64 + q) * TT;   // per-lane x index base
    const f4 zf4 = {0.f, 0.f, 0.f, 0.f};

    // ---- fully unrolled recurrence: all guards and LDS offsets fold statically ----
    #pragma unroll
    for (int t = 0; t < TT + 1; ++t) {
        const int tx = (t < TT) ? t : (TT - 1);   // t==11: x slots multiplied by 0 in dense A
        h4 Bv[4];
        #pragma unroll
        for (int k2 = 0; k2 < 4; ++k2) {
            const int xi = ibq + k2 * (16 * TT) + tx;
            unsigned int xw0 = 0u;
            unsigned int xw1 = (p == 3) ? 0x00003C00u : 0u;   // k=14 'one' slot
            if (p == 3)      xw0 = sxA[xi];                         // (x1,x2)
            else if (p == 2) xw1 = ((unsigned int)sxB[xi]) << 16;   // (-,x0)
            const unsigned int b0 = pkf16(hD[k2][0], hD[k2][1]) | xw0;
            const unsigned int b1 = pkf16(hD[k2][2], hD[k2][3]) | xw1;
            const u2 bb = {b0, b1};
            Bv[k2] = __builtin_bit_cast(h4, bb);
        }
        // ---- fused dense: logits += dw_{t-1}^T · h_{t-1} (B rows >=11 zeroed by A) ----
        if (t) {
            const h4 dA = *(const h4*)(sda + (t - 1) * 128 + lane * 2);
            #pragma unroll
            for (int k2 = 0; k2 < 4; ++k2)
                dC[k2] = __builtin_amdgcn_mfma_f32_16x16x16f16(dA, Bv[k2], dC[k2], 0, 0, 0);
        }
        // ---- gate MFMAs + fused nonlinearity ----
        // A pre-scaled: vz = -az*log2e, vv = -ar*log2e, vrh/vxh = -2log2e * (rh / xh)
        // tz=e^{-az}, tv=e^{-ar}, r=1/(1+tv), tu=e^{-2(r*rh+xh)}
        // h' = z*h + (1-z)*tanh(..) = [(h+tz) + tu*(h-tz)] / [(1+tz)(1+tu)]
        if (t < TT) {
            #pragma unroll
            for (int k2 = 0; k2 < 4; ++k2) {
                f4 vz  = __builtin_amdgcn_mfma_f32_16x16x16f16(Az,  Bv[k2], zf4, 0, 0, 0);
                f4 vv  = __builtin_amdgcn_mfma_f32_16x16x16f16(Ar,  Bv[k2], zf4, 0, 0, 0);
                f4 vrh = __builtin_amdgcn_mfma_f32_16x16x16f16(Arh, Bv[k2], zf4, 0, 0, 0);
                f4 vxh = __builtin_amdgcn_mfma_f32_16x16x16f16(Axh, Bv[k2], zf4, 0, 0, 0);
                #pragma unroll
                for (int r = 0; r < 4; ++r) {
                    const float tz = __builtin_amdgcn_exp2f(vz[r]);
                    const float tv = __builtin_amdgcn_exp2f(vv[r]);
                    const float rr = __builtin_amdgcn_rcpf(1.0f + tv);
                    const float tu = __builtin_amdgcn_exp2f(fmaf(rr, vrh[r], vxh[r]));
                    const float hp = hD[k2][r];
                    const float num = fmaf(tu, hp - tz, hp + tz);
                    const float den = (1.0f + tz) * (1.0f + tu);
                    hD[k2][r] = num * __builtin_amdgcn_rcpf(den);
                }
            }
        }
    }

    // ---- softmax over c per batch: lanes (0,q)<->(1,q) hold c=0..3 / 4..6 ----
    __syncthreads();           // everyone done reading x stage; reuse sxA as output stage
    float* sf = (float*)sxA;   // needs 7168 B <= 11264 B
    #pragma unroll
    for (int k2 = 0; k2 < 4; ++k2) {
        const float d0 = dC[k2][0], d1 = dC[k2][1], d2 = dC[k2][2], d3 = dC[k2][3];
        float mloc = fmaxf(fmaxf(d0, d1), d2);
        if (p == 0) mloc = fmaxf(mloc, d3);           // p==1: c=7 is padding, exclude
        const float m = fmaxf(mloc, __shfl_xor(mloc, 16, 64));
        const float e0 = __builtin_amdgcn_exp2f((d0 - m) * L2E);
        const float e1 = __builtin_amdgcn_exp2f((d1 - m) * L2E);
        const float e2 = __builtin_amdgcn_exp2f((d2 - m) * L2E);
        const float e3 = (p == 0) ? __builtin_amdgcn_exp2f((d3 - m) * L2E) : 0.0f;
        const float sl = e0 + e1 + e2 + e3;
        const float ssum = sl + __shfl_xor(sl, 16, 64);
        const float inv = __builtin_amdgcn_rcpf(ssum);
        if (p < 2) {
            const int bL = wave * 64 + k2 * 16 + q;
            float* dst = sf + bL * CC + p * 4;
            dst[0] = e0 * inv; dst[1] = e1 * inv; dst[2] = e2 * inv;
            if (p == 0) dst[3] = e3 * inv;
        }
    }
    __syncthreads();
    // ---- coalesced writeback ----
    {
        const long long obase = base * CC;
        const long long omax = (long long)Bt * CC;
        #pragma unroll
        for (int i = 0; i < CC; ++i) {
            const long long g = obase + tid + i * BLOCK;
            if (g < omax) out[g] = sf[tid + i * BLOCK];
        }
    }
}

extern "C" void kernel_launch(void* const* d_in, const int* in_sizes, int n_in,
                              void* d_out, int out_size, void* d_ws, size_t ws_size,
                              hipStream_t stream) {
    const float* x  = (const float*)d_in[0];
    const float* k  = (const float*)d_in[1];
    const float* rk = (const float*)d_in[2];
    const float* bi = (const float*)d_in[3];
    const float* dw = (const float*)d_in[4];
    const float* db = (const float*)d_in[5];
    float* out = (float*)d_out;
    float* ws  = (float*)d_ws;

    const int Bt = in_sizes[0] / TF;  // 1048576
    prep_weights<<<1, BLOCK, 0, stream>>>(k, rk, bi, dw, db, ws);
    const int grid = (Bt + BLOCK - 1) / BLOCK;
    gru_main<<<grid, BLOCK, 0, stream>>>(x, ws, out, Bt);
}

// Round 7
// 364.274 us; speedup vs baseline: 2.1323x; 2.1323x over previous
//
#include <hip/hip_runtime.h>

// Problem constants: B=1048576, T=11, F=3, H=11, C=7
#define TT 11
#define FF 3
#define HH 11
#define CC 7
#define TF 33      // T*F
#define GBLOCK 512   // gru_main block (8 waves)
#define PBLOCK 256   // prep_weights block
#define L2E 1.44269504088896340736f

typedef _Float16 h4 __attribute__((ext_vector_type(4)));   // one MFMA A/B fragment (2 VGPRs)
typedef float f4 __attribute__((ext_vector_type(4)));      // one MFMA C/D fragment
typedef unsigned int u2 __attribute__((ext_vector_type(2)));

// ws layout (dwords):
//  [0..511]    gate A-fragments  [4 gates][64 lanes][2 dwords]  (PRE-SCALED by -log2e / -2log2e)
//  [512..1919] dense A-fragments [11 t   ][64 lanes][2 dwords]
#define WS_GA 0
#define WS_DA 512
#define WS_TOT 1920

// Augmented weight matrix value, transposed form A'[row=n(gate out)][k]:
//  k=0..10 -> h_k coefficient, k=11..13 -> x_{k-11} coefficient, k=14 -> bias (B row 14 = 1.0), k=15 -> 0
__device__ __forceinline__ float gate_val(int g, int k, int n,
        const float* rk, const float* kk, const float* bias) {
    if (n >= HH) return 0.0f;
    if (g == 0 || g == 1) {            // z, r: full augmented row
        const int col = (g == 0 ? 0 : HH) + n;
        if (k < HH) return rk[k * TF + col];
        if (k < 14) return kk[(k - 11) * TF + col];
        if (k == 14) return bias[col] + bias[TF + col];
        return 0.0f;
    }
    const int col = 2 * HH + n;
    if (g == 2) {                      // rh: recurrent candidate part (+ recurrent bias)
        if (k < HH) return rk[k * TF + col];
        if (k == 14) return bias[TF + col];
        return 0.0f;
    }
    // g == 3, xh: input candidate part (+ input bias)
    if (k >= 11 && k < 14) return kk[(k - 11) * TF + col];
    if (k == 14) return bias[col];
    return 0.0f;
}

__global__ void prep_weights(const float* __restrict__ k,
                             const float* __restrict__ rk,
                             const float* __restrict__ bias,
                             const float* __restrict__ dw,
                             const float* __restrict__ db,
                             float* __restrict__ ws) {
    const int tid = threadIdx.x;
    unsigned int* wsu = (unsigned int*)ws;
    // gate A-frags: one (gate, lane) pair per thread (4*64 = 256 threads)
    // Pre-scale: z,r rows by -log2e (so exp2(az') = e^{-az}); rh,xh rows by -2log2e.
    if (tid < 256) {
        const int g = tid >> 6, l = tid & 63;
        const int n = l & 15, kb = 4 * (l >> 4);
        const float scale = (g < 2) ? -L2E : (-2.0f * L2E);
        unsigned short h[4];
        #pragma unroll
        for (int i = 0; i < 4; ++i) {
            const float v = gate_val(g, kb + i, n, rk, k, bias) * scale;
            h[i] = __builtin_bit_cast(unsigned short, (_Float16)v);
        }
        wsu[WS_GA + (g * 64 + l) * 2]     = h[0] | ((unsigned int)h[1] << 16);
        wsu[WS_GA + (g * 64 + l) * 2 + 1] = h[2] | ((unsigned int)h[3] << 16);
    }
    // dense A-frags: A'_t[row=c][k] = dw_t[k][c] for k<11; k=14,t=0 -> db[c] (ones-row trick)
    for (int idx = tid; idx < TT * 64; idx += PBLOCK) {
        const int t = idx >> 6, l = idx & 63;
        const int c = l & 15, kb = 4 * (l >> 4);
        unsigned short h[4];
        #pragma unroll
        for (int i = 0; i < 4; ++i) {
            const int kk2 = kb + i;
            float v = 0.0f;
            if (c < CC) {
                if (kk2 < HH) v = dw[(t * HH + kk2) * CC + c];
                else if (kk2 == 14 && t == 0) v = db[c];
            }
            h[i] = __builtin_bit_cast(unsigned short, (_Float16)v);
        }
        wsu[WS_DA + idx * 2]     = h[0] | ((unsigned int)h[1] << 16);
        wsu[WS_DA + idx * 2 + 1] = h[2] | ((unsigned int)h[3] << 16);
    }
}

__device__ __forceinline__ unsigned int pkf16(float a, float b) {
    return (unsigned int)__builtin_bit_cast(unsigned short, (_Float16)a) |
           ((unsigned int)__builtin_bit_cast(unsigned short, (_Float16)b) << 16);
}

__global__ __launch_bounds__(GBLOCK, 8) void gru_main(
    const float* __restrict__ x,   // [B, T*F] f32
    const float* __restrict__ ws,  // fragment-ordered weights
    float* __restrict__ out,       // [B, C]
    int Bt)
{
    // LDS: x-stage 6 B/(b,t) = 33792 B + dense frags 5632 B = 39424 B -> 4 blocks/CU = 32 waves/CU
    __shared__ unsigned int   sxA[GBLOCK * TT];    // (x1,x2) f16 pair      22528 B
    __shared__ unsigned short sxB[GBLOCK * TT];    // x0 f16                11264 B
    __shared__ float sda[TT * 128];                // dense A-frags          5632 B
    const int tid = threadIdx.x;
    const long long base = (long long)blockIdx.x * GBLOCK;

    // dense A-frags -> LDS (coalesced, once)
    for (int i = tid; i < TT * 128; i += GBLOCK) sda[i] = ws[WS_DA + i];

    const int lane = tid & 63, wave = tid >> 6;
    // gate A-frags -> registers (8 VGPRs total; all GRU weights+biases, pre-scaled)
    const h4* gfp = (const h4*)ws;
    const h4 Az  = gfp[lane];
    const h4 Ar  = gfp[64 + lane];
    const h4 Arh = gfp[128 + lane];
    const h4 Axh = gfp[192 + lane];

    // ---- coalesced x stage, f16-packed compact ----
    {
        const long long gbase = base * TF;
        const long long gmax = (long long)Bt * TF;
        unsigned short* sxA16 = (unsigned short*)sxA;
        #pragma unroll
        for (int i = 0; i < TF; ++i) {
            const int e = tid + i * GBLOCK;
            const long long g = gbase + e;
            const float v = (g < gmax) ? x[g] : 0.0f;
            const int b = e / TF, r = e % TF;
            const int t = r / FF, s = r % FF;
            const unsigned short hv = __builtin_bit_cast(unsigned short, (_Float16)v);
            if (s == 0) sxB[b * TT + t] = hv;                   // x0
            else        sxA16[(b * TT + t) * 2 + (s - 1)] = hv; // (x1,x2)
        }
    }
    __syncthreads();

    const int q = lane & 15, p = lane >> 4;

    // Per-tile state: hD[k2][r] = h[j = 4p+r][b = 16*k2 + q]  (D-fragment layout)
    // Invariants (A rows >= 11 are zero + nonlinearity maps 0 -> exactly 0):
    //   p==3: hD[k2][*] == 0 ; p==2: hD[k2][3] == 0  -> B-build can use plain ORs.
    float hD[4][4];
    f4 dC[4];
    #pragma unroll
    for (int k2 = 0; k2 < 4; ++k2) {
        dC[k2] = (f4){0.f, 0.f, 0.f, 0.f};
        #pragma unroll
        for (int r = 0; r < 4; ++r) hD[k2][r] = 0.0f;
    }

    const int ibq = (wave * 64 + q) * TT;   // per-lane x index base
    const f4 zf4 = {0.f, 0.f, 0.f, 0.f};

    #pragma unroll 1
    for (int t = 0; t < TT + 1; ++t) {
        const int tx = (t < TT) ? t : (TT - 1);   // t==11: x slots multiplied by 0 in dense A
        // ---- build B fragments: k=0..10 from hD (lane-local pass-through), 11..13 x, 14 one ----
        h4 Bv[4];
        #pragma unroll
        for (int k2 = 0; k2 < 4; ++k2) {
            const int xi = ibq + k2 * (16 * TT) + tx;
            unsigned int xw0 = 0u;
            unsigned int xw1 = (p == 3) ? 0x00003C00u : 0u;   // k=14 'one' slot
            if (p == 3)      xw0 = sxA[xi];                         // (x1,x2)
            else if (p == 2) xw1 = ((unsigned int)sxB[xi]) << 16;   // (-,x0)
            const unsigned int b0 = pkf16(hD[k2][0], hD[k2][1]) | xw0;
            const unsigned int b1 = pkf16(hD[k2][2], hD[k2][3]) | xw1;
            const u2 bb = {b0, b1};
            Bv[k2] = __builtin_bit_cast(h4, bb);
        }
        // ---- fused dense: logits += dw_{t-1}^T · h_{t-1} (B rows >=11 zeroed by A) ----
        if (t) {
            const h4 dA = *(const h4*)(sda + (t - 1) * 128 + lane * 2);
            #pragma unroll
            for (int k2 = 0; k2 < 4; ++k2)
                dC[k2] = __builtin_amdgcn_mfma_f32_16x16x16f16(dA, Bv[k2], dC[k2], 0, 0, 0);
        }
        // ---- gate MFMAs + fused nonlinearity ----
        // A pre-scaled: vz = -az*log2e, vv = -ar*log2e, vrh/vxh = -2log2e * (rh / xh)
        // tz=e^{-az}, tv=e^{-ar}, r=1/(1+tv), tu=e^{-2(r*rh+xh)}
        // h' = z*h + (1-z)*tanh(..) = [(h+tz) + tu*(h-tz)] / [(1+tz)(1+tu)]
        if (t < TT) {
            #pragma unroll
            for (int k2 = 0; k2 < 4; ++k2) {
                f4 vz  = __builtin_amdgcn_mfma_f32_16x16x16f16(Az,  Bv[k2], zf4, 0, 0, 0);
                f4 vv  = __builtin_amdgcn_mfma_f32_16x16x16f16(Ar,  Bv[k2], zf4, 0, 0, 0);
                f4 vrh = __builtin_amdgcn_mfma_f32_16x16x16f16(Arh, Bv[k2], zf4, 0, 0, 0);
                f4 vxh = __builtin_amdgcn_mfma_f32_16x16x16f16(Axh, Bv[k2], zf4, 0, 0, 0);
                #pragma unroll
                for (int r = 0; r < 4; ++r) {
                    const float tz = __builtin_amdgcn_exp2f(vz[r]);
                    const float tv = __builtin_amdgcn_exp2f(vv[r]);
                    const float rr = __builtin_amdgcn_rcpf(1.0f + tv);
                    const float tu = __builtin_amdgcn_exp2f(fmaf(rr, vrh[r], vxh[r]));
                    const float hp = hD[k2][r];
                    const float num = fmaf(tu, hp - tz, hp + tz);
                    const float den = (1.0f + tz) * (1.0f + tu);
                    hD[k2][r] = num * __builtin_amdgcn_rcpf(den);
                }
            }
        }
    }

    // ---- softmax over c per batch: lanes (0,q)<->(1,q) hold c=0..3 / 4..6 ----
    __syncthreads();           // everyone done reading x stage; reuse sxA as output stage
    float* sf = (float*)sxA;   // needs GBLOCK*7*4 = 14336 B <= 22528 B
    #pragma unroll
    for (int k2 = 0; k2 < 4; ++k2) {
        const float d0 = dC[k2][0], d1 = dC[k2][1], d2 = dC[k2][2], d3 = dC[k2][3];
        float mloc = fmaxf(fmaxf(d0, d1), d2);
        if (p == 0) mloc = fmaxf(mloc, d3);           // p==1: c=7 is padding, exclude
        const float m = fmaxf(mloc, __shfl_xor(mloc, 16, 64));
        const float e0 = __builtin_amdgcn_exp2f((d0 - m) * L2E);
        const float e1 = __builtin_amdgcn_exp2f((d1 - m) * L2E);
        const float e2 = __builtin_amdgcn_exp2f((d2 - m) * L2E);
        const float e3 = (p == 0) ? __builtin_amdgcn_exp2f((d3 - m) * L2E) : 0.0f;
        const float sl = e0 + e1 + e2 + e3;
        const float ssum = sl + __shfl_xor(sl, 16, 64);
        const float inv = __builtin_amdgcn_rcpf(ssum);
        if (p < 2) {
            const int bL = wave * 64 + k2 * 16 + q;
            float* dst = sf + bL * CC + p * 4;
            dst[0] = e0 * inv; dst[1] = e1 * inv; dst[2] = e2 * inv;
            if (p == 0) dst[3] = e3 * inv;
        }
    }
    __syncthreads();
    // ---- coalesced writeback ----
    {
        const long long obase = base * CC;
        const long long omax = (long long)Bt * CC;
        #pragma unroll
        for (int i = 0; i < CC; ++i) {
            const long long g = obase + tid + i * GBLOCK;
            if (g < omax) out[g] = sf[tid + i * GBLOCK];
        }
    }
}

extern "C" void kernel_launch(void* const* d_in, const int* in_sizes, int n_in,
                              void* d_out, int out_size, void* d_ws, size_t ws_size,
                              hipStream_t stream) {
    const float* x  = (const float*)d_in[0];
    const float* k  = (const float*)d_in[1];
    const float* rk = (const float*)d_in[2];
    const float* bi = (const float*)d_in[3];
    const float* dw = (const float*)d_in[4];
    const float* db = (const float*)d_in[5];
    float* out = (float*)d_out;
    float* ws  = (float*)d_ws;

    const int Bt = in_sizes[0] / TF;  // 1048576
    prep_weights<<<1, PBLOCK, 0, stream>>>(k, rk, bi, dw, db, ws);
    const int grid = (Bt + GBLOCK - 1) / GBLOCK;
    gru_main<<<grid, GBLOCK, 0, stream>>>(x, ws, out, Bt);
}

// Round 8
// 341.853 us; speedup vs baseline: 2.2722x; 1.0656x over previous
//
#include <hip/hip_runtime.h>

// Problem constants: B=1048576, T=11, F=3, H=11, C=7
#define TT 11
#define FF 3
#define HH 11
#define CC 7
#define TF 33      // T*F
#define GBLOCK 512   // gru_main block (8 waves)
#define PBLOCK 256   // prep_weights block
#define L2E 1.44269504088896340736f

typedef _Float16 h4 __attribute__((ext_vector_type(4)));   // one MFMA A/B fragment (2 VGPRs)
typedef float f4 __attribute__((ext_vector_type(4)));      // one MFMA C/D fragment
typedef unsigned int u2 __attribute__((ext_vector_type(2)));

// ws layout (dwords):
//  [0..511]    gate A-fragments  [4 gates][64 lanes][2 dwords]  (PRE-SCALED by -log2e / -2log2e)
//  [512..1919] dense A-fragments [11 t   ][64 lanes][2 dwords]
#define WS_GA 0
#define WS_DA 512
#define WS_TOT 1920

// Augmented weight matrix value, transposed form A'[row=n(gate out)][k]:
//  k=0..10 -> h_k coefficient, k=11..13 -> x_{k-11} coefficient, k=14 -> bias (B row 14 = 1.0), k=15 -> 0
__device__ __forceinline__ float gate_val(int g, int k, int n,
        const float* rk, const float* kk, const float* bias) {
    if (n >= HH) return 0.0f;
    if (g == 0 || g == 1) {            // z, r: full augmented row
        const int col = (g == 0 ? 0 : HH) + n;
        if (k < HH) return rk[k * TF + col];
        if (k < 14) return kk[(k - 11) * TF + col];
        if (k == 14) return bias[col] + bias[TF + col];
        return 0.0f;
    }
    const int col = 2 * HH + n;
    if (g == 2) {                      // rh: recurrent candidate part (+ recurrent bias)
        if (k < HH) return rk[k * TF + col];
        if (k == 14) return bias[TF + col];
        return 0.0f;
    }
    // g == 3, xh: input candidate part (+ input bias)
    if (k >= 11 && k < 14) return kk[(k - 11) * TF + col];
    if (k == 14) return bias[col];
    return 0.0f;
}

__global__ void prep_weights(const float* __restrict__ k,
                             const float* __restrict__ rk,
                             const float* __restrict__ bias,
                             const float* __restrict__ dw,
                             const float* __restrict__ db,
                             float* __restrict__ ws) {
    const int tid = threadIdx.x;
    unsigned int* wsu = (unsigned int*)ws;
    // gate A-frags: one (gate, lane) pair per thread (4*64 = 256 threads)
    // Pre-scale: z,r rows by -log2e (so exp2(az') = e^{-az}); rh,xh rows by -2log2e.
    if (tid < 256) {
        const int g = tid >> 6, l = tid & 63;
        const int n = l & 15, kb = 4 * (l >> 4);
        const float scale = (g < 2) ? -L2E : (-2.0f * L2E);
        unsigned short h[4];
        #pragma unroll
        for (int i = 0; i < 4; ++i) {
            const float v = gate_val(g, kb + i, n, rk, k, bias) * scale;
            h[i] = __builtin_bit_cast(unsigned short, (_Float16)v);
        }
        wsu[WS_GA + (g * 64 + l) * 2]     = h[0] | ((unsigned int)h[1] << 16);
        wsu[WS_GA + (g * 64 + l) * 2 + 1] = h[2] | ((unsigned int)h[3] << 16);
    }
    // dense A-frags: A'_t[row=c][k] = dw_t[k][c] for k<11; k=14,t=0 -> db[c] (ones-row trick)
    for (int idx = tid; idx < TT * 64; idx += PBLOCK) {
        const int t = idx >> 6, l = idx & 63;
        const int c = l & 15, kb = 4 * (l >> 4);
        unsigned short h[4];
        #pragma unroll
        for (int i = 0; i < 4; ++i) {
            const int kk2 = kb + i;
            float v = 0.0f;
            if (c < CC) {
                if (kk2 < HH) v = dw[(t * HH + kk2) * CC + c];
                else if (kk2 == 14 && t == 0) v = db[c];
            }
            h[i] = __builtin_bit_cast(unsigned short, (_Float16)v);
        }
        wsu[WS_DA + idx * 2]     = h[0] | ((unsigned int)h[1] << 16);
        wsu[WS_DA + idx * 2 + 1] = h[2] | ((unsigned int)h[3] << 16);
    }
}

__device__ __forceinline__ unsigned int pkf16(float a, float b) {
    return (unsigned int)__builtin_bit_cast(unsigned short, (_Float16)a) |
           ((unsigned int)__builtin_bit_cast(unsigned short, (_Float16)b) << 16);
}

// min-waves=4 (cap 128 regs): natural allocation (~36-50 regs) fits 8 waves/SIMD
// via the LDS-driven 4-blocks/CU without forcing a spill (round-7 lesson: (512,8)
// hard-capped 64 regs -> allocator squeezed to 32+32 and spilled ~180 MB scratch).
__global__ __launch_bounds__(GBLOCK, 4) void gru_main(
    const float* __restrict__ x,   // [B, T*F] f32
    const float* __restrict__ ws,  // fragment-ordered weights
    float* __restrict__ out,       // [B, C]
    int Bt)
{
    // LDS: x-stage 6 B/(b,t) = 33792 B + dense frags 5632 B = 39424 B -> 4 blocks/CU = 32 waves/CU
    __shared__ unsigned int   sxA[GBLOCK * TT];    // (x1,x2) f16 pair      22528 B
    __shared__ unsigned short sxB[GBLOCK * TT];    // x0 f16                11264 B
    __shared__ float sda[TT * 128];                // dense A-frags          5632 B
    const int tid = threadIdx.x;
    const long long base = (long long)blockIdx.x * GBLOCK;

    // dense A-frags -> LDS (coalesced, once)
    for (int i = tid; i < TT * 128; i += GBLOCK) sda[i] = ws[WS_DA + i];

    const int lane = tid & 63, wave = tid >> 6;
    // gate A-frags -> registers (8 VGPRs total; all GRU weights+biases, pre-scaled)
    const h4* gfp = (const h4*)ws;
    const h4 Az  = gfp[lane];
    const h4 Ar  = gfp[64 + lane];
    const h4 Arh = gfp[128 + lane];
    const h4 Axh = gfp[192 + lane];

    // ---- coalesced x stage, f16-packed compact ----
    {
        const long long gbase = base * TF;
        const long long gmax = (long long)Bt * TF;
        unsigned short* sxA16 = (unsigned short*)sxA;
        #pragma unroll
        for (int i = 0; i < TF; ++i) {
            const int e = tid + i * GBLOCK;
            const long long g = gbase + e;
            const float v = (g < gmax) ? x[g] : 0.0f;
            const int b = e / TF, r = e % TF;
            const int t = r / FF, s = r % FF;
            const unsigned short hv = __builtin_bit_cast(unsigned short, (_Float16)v);
            if (s == 0) sxB[b * TT + t] = hv;                   // x0
            else        sxA16[(b * TT + t) * 2 + (s - 1)] = hv; // (x1,x2)
        }
    }
    __syncthreads();

    const int q = lane & 15, p = lane >> 4;

    // Per-tile state: hD[k2][r] = h[j = 4p+r][b = 16*k2 + q]  (D-fragment layout)
    // Invariants (A rows >= 11 are zero + nonlinearity maps 0 -> exactly 0):
    //   p==3: hD[k2][*] == 0 ; p==2: hD[k2][3] == 0  -> B-build can use plain ORs.
    float hD[4][4];
    f4 dC[4];
    #pragma unroll
    for (int k2 = 0; k2 < 4; ++k2) {
        dC[k2] = (f4){0.f, 0.f, 0.f, 0.f};
        #pragma unroll
        for (int r = 0; r < 4; ++r) hD[k2][r] = 0.0f;
    }

    const int ibq = (wave * 64 + q) * TT;   // per-lane x index base
    const f4 zf4 = {0.f, 0.f, 0.f, 0.f};

    #pragma unroll 1
    for (int t = 0; t < TT + 1; ++t) {
        const int tx = (t < TT) ? t : (TT - 1);   // t==11: x slots multiplied by 0 in dense A
        // ---- build B fragments: k=0..10 from hD (lane-local pass-through), 11..13 x, 14 one ----
        h4 Bv[4];
        #pragma unroll
        for (int k2 = 0; k2 < 4; ++k2) {
            const int xi = ibq + k2 * (16 * TT) + tx;
            unsigned int xw0 = 0u;
            unsigned int xw1 = (p == 3) ? 0x00003C00u : 0u;   // k=14 'one' slot
            if (p == 3)      xw0 = sxA[xi];                         // (x1,x2)
            else if (p == 2) xw1 = ((unsigned int)sxB[xi]) << 16;   // (-,x0)
            const unsigned int b0 = pkf16(hD[k2][0], hD[k2][1]) | xw0;
            const unsigned int b1 = pkf16(hD[k2][2], hD[k2][3]) | xw1;
            const u2 bb = {b0, b1};
            Bv[k2] = __builtin_bit_cast(h4, bb);
        }
        // ---- fused dense: logits += dw_{t-1}^T · h_{t-1} (B rows >=11 zeroed by A) ----
        if (t) {
            const h4 dA = *(const h4*)(sda + (t - 1) * 128 + lane * 2);
            #pragma unroll
            for (int k2 = 0; k2 < 4; ++k2)
                dC[k2] = __builtin_amdgcn_mfma_f32_16x16x16f16(dA, Bv[k2], dC[k2], 0, 0, 0);
        }
        // ---- gate MFMAs + fused nonlinearity ----
        // A pre-scaled: vz = -az*log2e, vv = -ar*log2e, vrh/vxh = -2log2e * (rh / xh)
        // tz=e^{-az}, tv=e^{-ar}, r=1/(1+tv), tu=e^{-2(r*rh+xh)}
        // h' = z*h + (1-z)*tanh(..) = [(h+tz) + tu*(h-tz)] / [(1+tz)(1+tu)]
        if (t < TT) {
            #pragma unroll
            for (int k2 = 0; k2 < 4; ++k2) {
                f4 vz  = __builtin_amdgcn_mfma_f32_16x16x16f16(Az,  Bv[k2], zf4, 0, 0, 0);
                f4 vv  = __builtin_amdgcn_mfma_f32_16x16x16f16(Ar,  Bv[k2], zf4, 0, 0, 0);
                f4 vrh = __builtin_amdgcn_mfma_f32_16x16x16f16(Arh, Bv[k2], zf4, 0, 0, 0);
                f4 vxh = __builtin_amdgcn_mfma_f32_16x16x16f16(Axh, Bv[k2], zf4, 0, 0, 0);
                #pragma unroll
                for (int r = 0; r < 4; ++r) {
                    const float tz = __builtin_amdgcn_exp2f(vz[r]);
                    const float tv = __builtin_amdgcn_exp2f(vv[r]);
                    const float rr = __builtin_amdgcn_rcpf(1.0f + tv);
                    const float tu = __builtin_amdgcn_exp2f(fmaf(rr, vrh[r], vxh[r]));
                    const float hp = hD[k2][r];
                    const float num = fmaf(tu, hp - tz, hp + tz);
                    const float den = (1.0f + tz) * (1.0f + tu);
                    hD[k2][r] = num * __builtin_amdgcn_rcpf(den);
                }
            }
        }
    }

    // ---- softmax over c per batch: lanes (0,q)<->(1,q) hold c=0..3 / 4..6 ----
    __syncthreads();           // everyone done reading x stage; reuse sxA as output stage
    float* sf = (float*)sxA;   // needs GBLOCK*7*4 = 14336 B <= 22528 B
    #pragma unroll
    for (int k2 = 0; k2 < 4; ++k2) {
        const float d0 = dC[k2][0], d1 = dC[k2][1], d2 = dC[k2][2], d3 = dC[k2][3];
        float mloc = fmaxf(fmaxf(d0, d1), d2);
        if (p == 0) mloc = fmaxf(mloc, d3);           // p==1: c=7 is padding, exclude
        const float m = fmaxf(mloc, __shfl_xor(mloc, 16, 64));
        const float e0 = __builtin_amdgcn_exp2f((d0 - m) * L2E);
        const float e1 = __builtin_amdgcn_exp2f((d1 - m) * L2E);
        const float e2 = __builtin_amdgcn_exp2f((d2 - m) * L2E);
        const float e3 = (p == 0) ? __builtin_amdgcn_exp2f((d3 - m) * L2E) : 0.0f;
        const float sl = e0 + e1 + e2 + e3;
        const float ssum = sl + __shfl_xor(sl, 16, 64);
        const float inv = __builtin_amdgcn_rcpf(ssum);
        if (p < 2) {
            const int bL = wave * 64 + k2 * 16 + q;
            float* dst = sf + bL * CC + p * 4;
            dst[0] = e0 * inv; dst[1] = e1 * inv; dst[2] = e2 * inv;
            if (p == 0) dst[3] = e3 * inv;
        }
    }
    __syncthreads();
    // ---- coalesced writeback ----
    {
        const long long obase = base * CC;
        const long long omax = (long long)Bt * CC;
        #pragma unroll
        for (int i = 0; i < CC; ++i) {
            const long long g = obase + tid + i * GBLOCK;
            if (g < omax) out[g] = sf[tid + i * GBLOCK];
        }
    }
}

extern "C" void kernel_launch(void* const* d_in, const int* in_sizes, int n_in,
                              void* d_out, int out_size, void* d_ws, size_t ws_size,
                              hipStream_t stream) {
    const float* x  = (const float*)d_in[0];
    const float* k  = (const float*)d_in[1];
    const float* rk = (const float*)d_in[2];
    const float* bi = (const float*)d_in[3];
    const float* dw = (const float*)d_in[4];
    const float* db = (const float*)d_in[5];
    float* out = (float*)d_out;
    float* ws  = (float*)d_ws;

    const int Bt = in_sizes[0] / TF;  // 1048576
    prep_weights<<<1, PBLOCK, 0, stream>>>(k, rk, bi, dw, db, ws);
    const int grid = (Bt + GBLOCK - 1) / GBLOCK;
    gru_main<<<grid, GBLOCK, 0, stream>>>(x, ws, out, Bt);
}